// Round 9
// baseline (125.416 us; speedup 1.0000x reference)
//
#include <hip/hip_runtime.h>

typedef __attribute__((ext_vector_type(8))) short short8;
typedef __attribute__((ext_vector_type(4))) short short4v;
typedef __attribute__((ext_vector_type(4))) float floatx4;
typedef __attribute__((ext_vector_type(4))) unsigned short ushortx4;
typedef __attribute__((ext_vector_type(8))) unsigned short ushortx8;
typedef unsigned int u32;
typedef __attribute__((ext_vector_type(2))) u32 u32x2;
typedef __attribute__((ext_vector_type(4))) u32 u32x4;

#define MFMA_K32(A, B, C) __builtin_amdgcn_mfma_f32_16x16x32_bf16(A, B, C, 0, 0, 0)

#if __has_builtin(__builtin_amdgcn_mfma_f32_16x16x16bf16_1k)
#define HAVE_K16 1
#define MFMA_K16(A, B, C) __builtin_amdgcn_mfma_f32_16x16x16bf16_1k(A, B, C, 0, 0, 0)
#else
#define HAVE_K16 0  // fallback: zero-padded K32 (layout-consistent: same k slots in A and B)
#endif

#if __has_builtin(__builtin_amdgcn_exp2f)
#define EXP2(x) __builtin_amdgcn_exp2f(x)
#else
#define EXP2(x) exp2f(x)
#endif

// gfx9 waitcnt imm: vmcnt[3:0]|expcnt<<4|lgkmcnt<<8|vmcnt[5:4]<<14 (lgkm/exp = no-wait)
#define WAIT_VM6() __builtin_amdgcn_s_waitcnt(0x0F76)  // vmcnt(6): prev iter's 2 DMA + 4 V
#define WAIT_VM0() __builtin_amdgcn_s_waitcnt(0x0F70)  // vmcnt(0)
#define SB0() __builtin_amdgcn_sched_barrier(0)

__device__ __forceinline__ unsigned short f2bf(float f) {  // RNE
  u32 u = __builtin_bit_cast(u32, f);
  u += 0x7FFFu + ((u >> 16) & 1u);
  return (unsigned short)(u >> 16);
}
// async 16B/lane global->LDS: lds dst = wave-uniform base + lane*16
__device__ __forceinline__ void load_lds16(const void* g, void* l) {
  __builtin_amdgcn_global_load_lds((const __attribute__((address_space(1))) u32*)g,
                                   (__attribute__((address_space(3))) u32*)l, 16, 0, 0);
}

// Prep (512 blocks): K slab fp32->bf16 (plain) + V 64x64 tile -> vt[b][tile][w][d][16key]
// bf16 (wave-sliced so attn's V register loads are 512B-contiguous per instruction).
__global__ __launch_bounds__(256) void prep_kv(
    const float* __restrict__ k, const float* __restrict__ v,
    unsigned short* __restrict__ kb, unsigned short* __restrict__ vt) {
  __shared__ float tileT[64 * 68];  // [d][key]
  const int blk = blockIdx.x, tid = threadIdx.x;
  size_t base = (size_t)blk * 4096 + tid * 4;
#pragma unroll
  for (int i = 0; i < 4; i++) {
    size_t off = base + (size_t)i * 1024;
    floatx4 f = *(const floatx4*)(k + off);
    ushortx4 h;
    h[0] = f2bf(f[0]); h[1] = f2bf(f[1]); h[2] = f2bf(f[2]); h[3] = f2bf(f[3]);
    *(ushortx4*)(kb + off) = h;
  }
  // V tile transpose into LDS
  const int r = tid >> 2, c4 = (tid & 3) * 16;  // r = key-in-tile, c4 = d-chunk
  const float* vp = v + ((size_t)blk * 64 + r) * 64 + c4;
#pragma unroll
  for (int i = 0; i < 4; i++) {
    floatx4 f = *(const floatx4*)(vp + i * 4);
#pragma unroll
    for (int j = 0; j < 4; j++) tileT[(c4 + i * 4 + j) * 68 + r] = f[j];
  }
  __syncthreads();
  // out layout within tile (4096 ushorts): w*1024 + d*16 + key_in_window
  unsigned short* vo = vt + (size_t)blk * 4096;
#pragma unroll
  for (int i = 0; i < 2; i++) {
    const int u = tid + i * 256;               // 16B chunk id, 0..511
    const int w = u >> 7, d = (u >> 1) & 63, half = u & 1;
    const float* src = tileT + d * 68 + w * 16 + half * 8;
    floatx4 f0 = *(const floatx4*)src;
    floatx4 f1 = *(const floatx4*)(src + 4);
    ushortx8 h;
#pragma unroll
    for (int j = 0; j < 4; j++) { h[j] = f2bf(f0[j]); h[4 + j] = f2bf(f1[j]); }
    *(ushortx8*)(vo + u * 8) = h;
  }
}

// Attention: 512 blocks x 256 thr (4 waves), barrier-free hot loop. K: wave-private
// LDS double-buffer via DMA (XOR-swizzled, 2-way-free b128 reads). V: REGISTER
// double-buffer from global (512B-coalesced u32x2 loads; no LDS traffic/conflicts).
// Wave-local sync: s_waitcnt vmcnt(6) -- next tile's 6 loads stay in flight.
// S^T=K*Q^T -> C-layout == K16 B-frag layout -> P register-direct; l via ones-A K16.
__global__ __launch_bounds__(256, 2) void attn(
    const float* __restrict__ q, const unsigned short* __restrict__ kb,
    const unsigned short* __restrict__ vt, const float* __restrict__ mask,
    float* __restrict__ out) {
  // loop: 4 waves x 2 bufs x 1024 ushorts (K only) = 16384 B
  // epilogue: obuf 2x[64][72] fp32 (36864) + lbuf [4][64] (1024) = 37888 B
  __shared__ __align__(16) char smem_raw[37888];
  unsigned short* smem = (unsigned short*)smem_raw;
  const int tid = threadIdx.x;
  const int wave = tid >> 6, lane = tid & 63;
  const int c = lane & 15, quad = lane >> 4;
  const int b = blockIdx.x & 7, qt = blockIdx.x >> 3;  // blk%8=batch -> per-XCD L2 locality
  const int q0 = qt * 64;

  const unsigned short* kB = kb + (size_t)b * (4096 * 64);
  const unsigned short* vtB = vt + (size_t)b * (64 * 4096);

  // Q B-frags (B[k=d=kc*32+quad*8+j][n=q=c]), loop-invariant; fold (1/8)*log2(e)
  const float qscale = 0.18033688011112042f;
  short8 qf[4][2];
#pragma unroll
  for (int nt = 0; nt < 4; nt++)
#pragma unroll
    for (int kc = 0; kc < 2; kc++) {
      const float* qp = q + ((size_t)b * 4096 + q0 + nt * 16 + c) * 64 + kc * 32 + quad * 8;
      floatx4 f0 = *(const floatx4*)qp;
      floatx4 f1 = *(const floatx4*)(qp + 4);
      short8 s;
#pragma unroll
      for (int j = 0; j < 4; j++) {
        s[j] = (short)f2bf(f0[j] * qscale);
        s[4 + j] = (short)f2bf(f1[j] * qscale);
      }
      qf[nt][kc] = s;
    }

  floatx4 o[4][4], o_l[4];  // O^T[d=mt*16+quad*4+r][q=nt*16+c]; o_l rows all equal l
#pragma unroll
  for (int mt = 0; mt < 4; mt++)
#pragma unroll
    for (int nt = 0; nt < 4; nt++) o[mt][nt] = (floatx4){0.f, 0.f, 0.f, 0.f};
#pragma unroll
  for (int nt = 0; nt < 4; nt++) o_l[nt] = (floatx4){0.f, 0.f, 0.f, 0.f};

#if HAVE_K16
  short4v ones_a;
#pragma unroll
  for (int j = 0; j < 4; j++) ones_a[j] = (short)0x3F80;
#else
  short8 ones_a;
#pragma unroll
  for (int j = 0; j < 8; j++) ones_a[j] = (short)0x3F80;
#endif

  const int r8 = lane >> 3, cs8 = lane & 7;
  unsigned short* wbase = smem + wave * 2048;  // 2 K bufs x 1024 ushorts, wave-private
  const unsigned short* gK0 = kB + (size_t)(wave * 16 + r8) * 64 + (cs8 ^ r8) * 8;
  // V slice base for this wave (advances 4096/tile); per-lane frag offset
  const unsigned short* gV0 = vtB + wave * 1024;
  const int voff = (c * 16 + quad * 4);  // + mt*256 within slice

  auto stageK = [&](int t, int buf) {
    unsigned short* Kd = wbase + buf * 1024;
    const unsigned short* gk = gK0 + (size_t)t * 4096;
    load_lds16(gk, Kd);                 // K window rows 0-7 (phys slot = logical^row&7)
    load_lds16(gk + 8 * 64, Kd + 512);  // rows 8-15
  };
  auto loadV = [&](u32x2* vv, int t) {
    const unsigned short* gv = gV0 + (size_t)t * 4096 + voff;
#pragma unroll
    for (int mt = 0; mt < 4; mt++) vv[mt] = *(const u32x2*)(gv + mt * 256);
  };

  auto compute = [&](const unsigned short* Kbuf, const u32x2* vv) {
    // K A-frags (A[m=key=c][k=d]); phys slot = (kc*4+quad)^(c&7)  [2-way, free]
    short8 kf[2];
#pragma unroll
    for (int kc = 0; kc < 2; kc++)
      kf[kc] = *(const short8*)(Kbuf + c * 64 + ((kc * 4 + quad) ^ (c & 7)) * 8);
#pragma unroll
    for (int nt = 0; nt < 4; nt++) {
      floatx4 s = (floatx4){0.f, 0.f, 0.f, 0.f};
      s = MFMA_K32(kf[0], qf[nt][0], s);
      s = MFMA_K32(kf[1], qf[nt][1], s);
      // P^T[key=quad*4+r][q=nt*16+c] = exp2(s[r]); trunc via perm hi16
      u32 u0 = __builtin_bit_cast(u32, EXP2(s[0]));
      u32 u1 = __builtin_bit_cast(u32, EXP2(s[1]));
      u32 u2 = __builtin_bit_cast(u32, EXP2(s[2]));
      u32 u3 = __builtin_bit_cast(u32, EXP2(s[3]));
      u32 plo = __builtin_amdgcn_perm(u1, u0, 0x07060302u);
      u32 phi = __builtin_amdgcn_perm(u3, u2, 0x07060302u);
#if HAVE_K16
      short4v pf = __builtin_bit_cast(short4v, (u32x2){plo, phi});
#pragma unroll
      for (int mt = 0; mt < 4; mt++)
        o[mt][nt] = MFMA_K16(__builtin_bit_cast(short4v, vv[mt]), pf, o[mt][nt]);
      o_l[nt] = MFMA_K16(ones_a, pf, o_l[nt]);  // l rows: Sum_k P^T[k][q]
#else
      short8 pf = __builtin_bit_cast(short8, (u32x4){plo, phi, 0u, 0u});
#pragma unroll
      for (int mt = 0; mt < 4; mt++) {
        short8 va = __builtin_bit_cast(short8, (u32x4){vv[mt][0], vv[mt][1], 0u, 0u});
        o[mt][nt] = MFMA_K32(va, pf, o[mt][nt]);
      }
      o_l[nt] = MFMA_K32(ones_a, pf, o_l[nt]);
#endif
    }
  };

  u32x2 vvA[4], vvB[4];
  stageK(0, 0);
  loadV(vvA, 0);

#pragma unroll 1
  for (int tt = 0; tt < 32; tt++) {
    const int t0 = 2 * tt, t1 = t0 + 1;
    // half A: prefetch t1, wait t0's group (6 newer stay in flight), compute t0
    stageK(t1, 1);
    loadV(vvB, t1);
    WAIT_VM6();
    SB0();
    compute(wbase, vvA);
    // half B: prefetch t0+2, wait t1's group, compute t1
    if (tt < 31) {
      stageK(t0 + 2, 0);
      loadV(vvA, t0 + 2);
      WAIT_VM6();
    } else {
      WAIT_VM0();
    }
    SB0();
    compute(wbase + 1024, vvB);
  }

  // ---- merge 4 wave-partials (first barriers since loop start) ----
  __syncthreads();
  float* obuf = (float*)smem_raw;  // 2 x [64 q][72]
  float* lbuf = obuf + 9216;       // [4 waves][64 q]
  if (lane < 16) {
#pragma unroll
    for (int nt = 0; nt < 4; nt++) lbuf[wave * 64 + nt * 16 + c] = o_l[nt][0];
  }
  if (wave < 2) {
    float* ob = obuf + wave * 4608;
#pragma unroll
    for (int mt = 0; mt < 4; mt++)
#pragma unroll
      for (int nt = 0; nt < 4; nt++)
        *(floatx4*)(ob + (nt * 16 + c) * 72 + mt * 16 + quad * 4) = o[mt][nt];
  }
  __syncthreads();
  if (wave >= 2) {
    float* ob = obuf + (wave - 2) * 4608;
#pragma unroll
    for (int mt = 0; mt < 4; mt++)
#pragma unroll
      for (int nt = 0; nt < 4; nt++) {
        float* a = ob + (nt * 16 + c) * 72 + mt * 16 + quad * 4;
        floatx4 cur = *(floatx4*)a;
        *(floatx4*)a = cur + o[mt][nt];
      }
  }
  __syncthreads();

  // out = O/l * mask, coalesced float4 stores
  const int row = tid >> 2, dg = (tid & 3) * 16;
  const float l = lbuf[row] + lbuf[64 + row] + lbuf[128 + row] + lbuf[192 + row];
  const float sc = mask[b * 4096 + q0 + row] / l;
  float* op = out + ((size_t)b * 4096 + q0 + row) * 64 + dg;
#pragma unroll
  for (int i = 0; i < 4; i++) {
    floatx4 a = *(const floatx4*)(obuf + row * 72 + dg + i * 4);
    floatx4 b2 = *(const floatx4*)(obuf + 4608 + row * 72 + dg + i * 4);
    *(floatx4*)(op + i * 4) = (a + b2) * sc;
  }
}

extern "C" void kernel_launch(void* const* d_in, const int* in_sizes, int n_in,
                              void* d_out, int out_size, void* d_ws, size_t ws_size,
                              hipStream_t stream) {
  const float* q = (const float*)d_in[0];
  const float* k = (const float*)d_in[1];
  const float* v = (const float*)d_in[2];
  const float* mask = (const float*)d_in[3];
  unsigned short* kb = (unsigned short*)d_ws;  // 4 MB
  unsigned short* vt = kb + 8 * 4096 * 64;     // 4 MB (needs ws >= 8 MB)
  prep_kv<<<512, 256, 0, stream>>>(k, v, kb, vt);
  attn<<<512, 256, 0, stream>>>(q, kb, vt, mask, (float*)d_out);
}

// Round 10
// 115.866 us; speedup vs baseline: 1.0824x; 1.0824x over previous
//
#include <hip/hip_runtime.h>

typedef __attribute__((ext_vector_type(8))) short short8;
typedef __attribute__((ext_vector_type(4))) float floatx4;
typedef __attribute__((ext_vector_type(4))) unsigned short ushortx4;
typedef __attribute__((ext_vector_type(8))) unsigned short ushortx8;
typedef unsigned int u32;
typedef __attribute__((ext_vector_type(2))) u32 u32x2;
typedef __attribute__((ext_vector_type(4))) u32 u32x4;

#define MFMA_K32(A, B, C) __builtin_amdgcn_mfma_f32_16x16x32_bf16(A, B, C, 0, 0, 0)

#if __has_builtin(__builtin_amdgcn_exp2f)
#define EXP2(x) __builtin_amdgcn_exp2f(x)
#else
#define EXP2(x) exp2f(x)
#endif

// gfx9 waitcnt imm: vmcnt[3:0] | expcnt<<4 | lgkmcnt<<8 | vmcnt[5:4]<<14 (exp/lgkm = no-wait)
#define WAIT_VM12() __builtin_amdgcn_s_waitcnt(0x0F7C)  // keep 12 newest in flight
#define WAIT_VM8() __builtin_amdgcn_s_waitcnt(0x0F78)
#define WAIT_VM0() __builtin_amdgcn_s_waitcnt(0x0F70)
#define SB0() __builtin_amdgcn_sched_barrier(0)

__device__ __forceinline__ unsigned short f2bf(float f) {  // RNE
  u32 u = __builtin_bit_cast(u32, f);
  u += 0x7FFFu + ((u >> 16) & 1u);
  return (unsigned short)(u >> 16);
}
// async 16B/lane global->LDS: lds dst = wave-uniform base + lane*16
__device__ __forceinline__ void load_lds16(const void* g, void* l) {
  __builtin_amdgcn_global_load_lds((const __attribute__((address_space(1))) u32*)g,
                                   (__attribute__((address_space(3))) u32*)l, 16, 0, 0);
}

// Prep (512 blocks): K slab fp32->bf16 (plain [b][key][d]) + V 64-key tile ->
// vt[b][t*4+w][d][32key] bf16 (32-key wave windows, natural key order inside window).
__global__ __launch_bounds__(256) void prep_kv(
    const float* __restrict__ k, const float* __restrict__ v,
    unsigned short* __restrict__ kb, unsigned short* __restrict__ vt) {
  __shared__ float tileT[64 * 68];  // [d][key-in-64]
  const int blk = blockIdx.x, tid = threadIdx.x;
  size_t base = (size_t)blk * 4096 + tid * 4;
#pragma unroll
  for (int i = 0; i < 4; i++) {
    size_t off = base + (size_t)i * 1024;
    floatx4 f = *(const floatx4*)(k + off);
    ushortx4 h;
    h[0] = f2bf(f[0]); h[1] = f2bf(f[1]); h[2] = f2bf(f[2]); h[3] = f2bf(f[3]);
    *(ushortx4*)(kb + off) = h;
  }
  // V: block = (b, h) covering keys [h*64, h*64+64) -> windows (t=h>>1, w=2*(h&1)+s)
  const int b = blk >> 6, h = blk & 63;
  const int r = tid >> 2, c4 = (tid & 3) * 16;
  const float* vp = v + ((size_t)b * 4096 + h * 64 + r) * 64 + c4;
#pragma unroll
  for (int i = 0; i < 4; i++) {
    floatx4 f = *(const floatx4*)(vp + i * 4);
#pragma unroll
    for (int j = 0; j < 4; j++) tileT[(c4 + i * 4 + j) * 68 + r] = f[j];
  }
  __syncthreads();
  const int d = tid >> 2, g = tid & 3;
  unsigned short* vb = vt + (size_t)b * 262144 + ((h >> 1) * 4 + (h & 1) * 2) * 2048;
#pragma unroll
  for (int s = 0; s < 2; s++) {
    const float* src = tileT + d * 68 + s * 32 + g * 8;
    floatx4 f0 = *(const floatx4*)src;
    floatx4 f1 = *(const floatx4*)(src + 4);
    ushortx8 hh;
#pragma unroll
    for (int j = 0; j < 4; j++) { hh[j] = f2bf(f0[j]); hh[4 + j] = f2bf(f1[j]); }
    *(ushortx8*)(vb + s * 2048 + d * 32 + g * 8) = hh;
  }
}

// Attention: 512 blocks x 256 thr (4 waves), barrier-free, software-pipelined:
// 32-key wave windows; K staged via DMA 2 tiles ahead (4 LDS bufs, row-PERMUTED so
// two 16-key QK tiles concatenate into one K32 PV B-frag); V register ping-pong
// 1 tile ahead; per-iter wait = s_waitcnt vmcnt(12) (12 newer loads stay in flight).
// S^T=K*Q^T -> C-layout==PV B-frag layout -> P register-direct; l via ones-A K32.
__global__ __launch_bounds__(256, 2) void attn(
    const float* __restrict__ q, const unsigned short* __restrict__ kb,
    const unsigned short* __restrict__ vt, const float* __restrict__ mask,
    float* __restrict__ out) {
  // loop: 4 waves x 4 K bufs x 2048 ushorts = 65536 B (wave-private)
  // epilogue reuses: obuf 2x[64][72] fp32 + lbuf [4][64] = 37888 B
  __shared__ __align__(16) char smem_raw[65536];
  unsigned short* smem = (unsigned short*)smem_raw;
  const int tid = threadIdx.x;
  const int wave = tid >> 6, lane = tid & 63;
  const int c = lane & 15, quad = lane >> 4;
  const int b = blockIdx.x & 7, qt = blockIdx.x >> 3;  // blk%8=batch -> per-XCD L2 locality
  const int q0 = qt * 64;

  const unsigned short* kB = kb + (size_t)b * (4096 * 64);
  const unsigned short* vtB = vt + (size_t)b * 262144;

  // Q B-frags (B[k=d=kc*32+quad*8+j][n=q=c]), loop-invariant; fold (1/8)*log2(e)
  const float qscale = 0.18033688011112042f;
  short8 qf[4][2];
#pragma unroll
  for (int nt = 0; nt < 4; nt++)
#pragma unroll
    for (int kc = 0; kc < 2; kc++) {
      const float* qp = q + ((size_t)b * 4096 + q0 + nt * 16 + c) * 64 + kc * 32 + quad * 8;
      floatx4 f0 = *(const floatx4*)qp;
      floatx4 f1 = *(const floatx4*)(qp + 4);
      short8 s;
#pragma unroll
      for (int j = 0; j < 4; j++) {
        s[j] = (short)f2bf(f0[j] * qscale);
        s[4 + j] = (short)f2bf(f1[j] * qscale);
      }
      qf[nt][kc] = s;
    }

  floatx4 o[4][4], o_l[4];  // O^T[d=mt*16+quad*4+r][q=nt*16+c]; o_l rows all equal l
#pragma unroll
  for (int mt = 0; mt < 4; mt++)
#pragma unroll
    for (int nt = 0; nt < 4; nt++) o[mt][nt] = (floatx4){0.f, 0.f, 0.f, 0.f};
#pragma unroll
  for (int nt = 0; nt < 4; nt++) o_l[nt] = (floatx4){0.f, 0.f, 0.f, 0.f};

  short8 ones8;
#pragma unroll
  for (int j = 0; j < 8; j++) ones8[j] = (short)0x3F80;

  const int r8 = lane >> 3, cs8 = lane & 7;
  const int klane = (r8 >> 2) * 8 + (r8 & 3);  // row-permutation: C row (quad,r) -> key quad*8+r
  unsigned short* wbase = smem + wave * 8192;  // 4 bufs x 2048
  const unsigned short* gK0 = kB + (size_t)(wave * 32 + klane) * 64 + (cs8 ^ r8) * 8;
  const unsigned short* gV0 = vtB + wave * 2048 + c * 32 + quad * 8;

  auto stageK = [&](int t, int buf) {  // 4KB: tileA (keys {q8+0..3}) | tileB ({q8+4..7})
    unsigned short* Kd = wbase + buf * 2048;
    const unsigned short* gk = gK0 + (size_t)t * 8192;
    load_lds16(gk, Kd);                   // tileA rows 0-7   (key off  0)
    load_lds16(gk + 16 * 64, Kd + 512);   // tileA rows 8-15  (key off 16)
    load_lds16(gk + 4 * 64, Kd + 1024);   // tileB rows 0-7   (key off  4)
    load_lds16(gk + 20 * 64, Kd + 1536);  // tileB rows 8-15  (key off 20)
  };
  auto loadV = [&](u32x4* vv, int t) {  // 4 x 1KB-coalesced register loads
    const unsigned short* gv = gV0 + (size_t)t * 8192;
#pragma unroll
    for (int mt = 0; mt < 4; mt++) vv[mt] = *(const u32x4*)(gv + mt * 512);
  };

  auto compute = [&](const unsigned short* Kbuf, const u32x4* vv) {
    short8 kfA[2], kfB[2];  // A[m=key][k=d]; phys slot = (kc*4+quad)^(c&7)
#pragma unroll
    for (int kc = 0; kc < 2; kc++) {
      const int sl = ((kc * 4 + quad) ^ (c & 7)) * 8;
      kfA[kc] = *(const short8*)(Kbuf + c * 64 + sl);
      kfB[kc] = *(const short8*)(Kbuf + 1024 + c * 64 + sl);
    }
#pragma unroll
    for (int nt = 0; nt < 4; nt++) {
      floatx4 sA = (floatx4){0.f, 0.f, 0.f, 0.f}, sB = sA;
      sA = MFMA_K32(kfA[0], qf[nt][0], sA);
      sA = MFMA_K32(kfA[1], qf[nt][1], sA);
      sB = MFMA_K32(kfB[0], qf[nt][0], sB);
      sB = MFMA_K32(kfB[1], qf[nt][1], sB);
      // P^T[key=quad*8+j][q=nt*16+c]: A gives j=0..3, B gives j=4..7 (row-permuted staging)
      u32 a0 = __builtin_bit_cast(u32, EXP2(sA[0]));
      u32 a1 = __builtin_bit_cast(u32, EXP2(sA[1]));
      u32 a2 = __builtin_bit_cast(u32, EXP2(sA[2]));
      u32 a3 = __builtin_bit_cast(u32, EXP2(sA[3]));
      u32 b0 = __builtin_bit_cast(u32, EXP2(sB[0]));
      u32 b1 = __builtin_bit_cast(u32, EXP2(sB[1]));
      u32 b2 = __builtin_bit_cast(u32, EXP2(sB[2]));
      u32 b3 = __builtin_bit_cast(u32, EXP2(sB[3]));
      u32x4 pw = {__builtin_amdgcn_perm(a1, a0, 0x07060302u),
                  __builtin_amdgcn_perm(a3, a2, 0x07060302u),
                  __builtin_amdgcn_perm(b1, b0, 0x07060302u),
                  __builtin_amdgcn_perm(b3, b2, 0x07060302u)};
      short8 pf = __builtin_bit_cast(short8, pw);  // K32 B-frag: B[k=quad*8+j][n=c]
#pragma unroll
      for (int mt = 0; mt < 4; mt++)
        o[mt][nt] = MFMA_K32(__builtin_bit_cast(short8, vv[mt]), pf, o[mt][nt]);
      o_l[nt] = MFMA_K32(ones8, pf, o_l[nt]);  // l rows: Sum_k P^T[k][q]
    }
  };

  u32x4 vvA[4], vvB[4];
  stageK(0, 0);
  loadV(vvA, 0);
  stageK(1, 1);

#pragma unroll 1
  for (int tt = 0; tt < 16; tt++) {
    const int t0 = 2 * tt, t1 = t0 + 1;
    // iter t0: issue V(t0+1), K(t0+2); wait leaves K(t0+1),V(t0+1),K(t0+2) in flight
    loadV(vvB, t1);
    if (t0 + 2 < 32) { stageK(t0 + 2, (t0 + 2) & 3); WAIT_VM12(); }
    else { WAIT_VM8(); }  // t0=30: K31 + V31 outstanding
    SB0();
    compute(wbase + (t0 & 3) * 2048, vvA);
    // iter t1
    if (t1 + 2 < 32) { loadV(vvA, t1 + 1); stageK(t1 + 2, (t1 + 2) & 3); WAIT_VM12(); }
    else { WAIT_VM0(); }  // t1=31
    SB0();
    compute(wbase + (t1 & 3) * 2048, vvB);
  }

  // ---- merge 4 wave-partials (first barriers since loop start) ----
  __syncthreads();
  float* obuf = (float*)smem_raw;  // 2 x [64 q][72]
  float* lbuf = obuf + 9216;       // [4 waves][64 q]
  if (lane < 16) {
#pragma unroll
    for (int nt = 0; nt < 4; nt++) lbuf[wave * 64 + nt * 16 + c] = o_l[nt][0];
  }
  if (wave < 2) {
    float* ob = obuf + wave * 4608;
#pragma unroll
    for (int mt = 0; mt < 4; mt++)
#pragma unroll
      for (int nt = 0; nt < 4; nt++)
        *(floatx4*)(ob + (nt * 16 + c) * 72 + mt * 16 + quad * 4) = o[mt][nt];
  }
  __syncthreads();
  if (wave >= 2) {
    float* ob = obuf + (wave - 2) * 4608;
#pragma unroll
    for (int mt = 0; mt < 4; mt++)
#pragma unroll
      for (int nt = 0; nt < 4; nt++) {
        float* a = ob + (nt * 16 + c) * 72 + mt * 16 + quad * 4;
        floatx4 cur = *(floatx4*)a;
        *(floatx4*)a = cur + o[mt][nt];
      }
  }
  __syncthreads();

  // out = O/l * mask, coalesced float4 stores
  const int row = tid >> 2, dg = (tid & 3) * 16;
  const float l = lbuf[row] + lbuf[64 + row] + lbuf[128 + row] + lbuf[192 + row];
  const float sc = mask[b * 4096 + q0 + row] / l;
  float* op = out + ((size_t)b * 4096 + q0 + row) * 64 + dg;
#pragma unroll
  for (int i = 0; i < 4; i++) {
    floatx4 a = *(const floatx4*)(obuf + row * 72 + dg + i * 4);
    floatx4 b2 = *(const floatx4*)(obuf + 4608 + row * 72 + dg + i * 4);
    *(floatx4*)(op + i * 4) = (a + b2) * sc;
  }
}

extern "C" void kernel_launch(void* const* d_in, const int* in_sizes, int n_in,
                              void* d_out, int out_size, void* d_ws, size_t ws_size,
                              hipStream_t stream) {
  const float* q = (const float*)d_in[0];
  const float* k = (const float*)d_in[1];
  const float* v = (const float*)d_in[2];
  const float* mask = (const float*)d_in[3];
  unsigned short* kb = (unsigned short*)d_ws;  // 4 MB
  unsigned short* vt = kb + 8 * 4096 * 64;     // 4 MB (needs ws >= 8 MB)
  prep_kv<<<512, 256, 0, stream>>>(k, v, kb, vt);
  attn<<<512, 256, 0, stream>>>(q, kb, vt, mask, (float*)d_out);
}